// Round 23
// baseline (95.231 us; speedup 1.0000x reference)
//
#include <hip/hip_runtime.h>
#include <hip/hip_bf16.h>

typedef unsigned int uint;
typedef unsigned short ushort;
typedef _Float16 f16;
typedef __attribute__((ext_vector_type(4))) float f32x4;
typedef __attribute__((ext_vector_type(8))) _Float16 f16x8;
typedef __attribute__((ext_vector_type(8))) ushort ushort8;

#define MFMAH(a, b, c) __builtin_amdgcn_mfma_f32_16x16x32_f16((a), (b), (c), 0, 0, 0)

#if __has_builtin(__builtin_amdgcn_permlane32_swap) && __has_builtin(__builtin_amdgcn_permlane16_swap)
#define HAVE_PERMLANE_SWAP 1
#else
#define HAVE_PERMLANE_SWAP 0
#endif

// raw v_exp_f32: 1 instruction; denormal results flush to 0 (fine: P < 2^-126 is dead)
__device__ __forceinline__ float exp2_raw(float x) {
    return __builtin_amdgcn_exp2f(x);
}

__device__ __forceinline__ ushort f2h(float x) {
    f16 h = (f16)x;                       // RNE
    return __builtin_bit_cast(ushort, h);
}
// pack two f32 -> u32 of 2 fp16 (lo in [15:0]), RTZ — fine for P in [0,256]
__device__ __forceinline__ uint pk_f16(float lo, float hi) {
    auto t = __builtin_amdgcn_cvt_pkrtz(lo, hi);   // __fp16 ext_vector(2)
    return __builtin_bit_cast(uint, t);
}

__device__ __forceinline__ void gload_lds16(const void* g, void* l) {
    __builtin_amdgcn_global_load_lds(
        (const __attribute__((address_space(1))) void*)g,
        (__attribute__((address_space(3))) void*)l, 16, 0, 0);
}

// ------- fused fp32 -> fp16 conversion for x, Wq, Wk, Wv (one launch) -------
__global__ __launch_bounds__(256) void cvt_all(const float* __restrict__ x,
                                               const float* __restrict__ Wq,
                                               const float* __restrict__ Wk,
                                               const float* __restrict__ Wv,
                                               ushort* __restrict__ xf,
                                               ushort* __restrict__ wf) {
    const int blk = blockIdx.x;
    const float* src;
    ushort* dst;
    int i;   // 8-elem chunk index within the source
    if (blk < 2048) {
        src = x;  dst = xf;              i = blk * 256 + threadIdx.x;
    } else if (blk < 2560) {
        src = Wq; dst = wf;              i = (blk - 2048) * 256 + threadIdx.x;
    } else if (blk < 3072) {
        src = Wk; dst = wf + 1024 * 1024; i = (blk - 2560) * 256 + threadIdx.x;
    } else {
        src = Wv; dst = wf + 2 * 1024 * 1024; i = (blk - 3072) * 256 + threadIdx.x;
    }
    const float4* s4 = reinterpret_cast<const float4*>(src);
    float4 a = s4[2 * i], b = s4[2 * i + 1];
    float v[8] = {a.x, a.y, a.z, a.w, b.x, b.y, b.z, b.w};
    ushort8 o;
#pragma unroll
    for (int j = 0; j < 8; ++j) o[j] = f2h(v[j]);
    *reinterpret_cast<ushort8*>(dst + i * 8) = o;
}

// ---------------- fused QKV projection GEMM (fp16 single-term) ----------------
// z=0: Q scaled by log2(e), fp16. z=1: K fp16. z=2: V fp16, written TRANSPOSED
// to vt[bh][d][s].
__global__ __launch_bounds__(256, 3) void qkv_gemm(const ushort* __restrict__ xf,
                                                   const ushort* __restrict__ wf,
                                                   const float* __restrict__ bq,
                                                   const float* __restrict__ bk,
                                                   const float* __restrict__ bv,
                                                   ushort* __restrict__ qh,
                                                   ushort* __restrict__ kh,
                                                   ushort* __restrict__ vt) {
    __shared__ ushort Asf[128 * 64];
    __shared__ ushort Bsf[128 * 64];
    const int tid = threadIdx.x;
    const int l = tid & 63, w = tid >> 6;
    const int lrow = l & 15, lhi = l >> 4;
    const int wr = w >> 1, wc = w & 1;
    const int m0 = blockIdx.x * 128;
    const int n0 = blockIdx.y * 128;
    const int z = blockIdx.z;
    const ushort* wz = wf + z * (1024 * 1024);
    const float* bias = (z == 0) ? bq : (z == 1) ? bk : bv;

    f32x4 acc[4][4] = {};
    const int srow = w * 32 + (l >> 3);               // +i*8
    const int scol = ((l & 7) ^ (l >> 3)) * 8;        // pre-swizzled k-col (rule #21)
    const int lds0 = w * 2048;                        // +i*512
    const int arow = wr * 64 + lrow;
    const int brow = wc * 64 + lrow;

    for (int kt = 0; kt < 16; ++kt) {
        const int kb = kt * 64;
#pragma unroll
        for (int i = 0; i < 4; ++i) {
            gload_lds16(xf + (m0 + srow + i * 8) * 1024 + kb + scol, &Asf[lds0 + i * 512]);
            gload_lds16(wz + (n0 + srow + i * 8) * 1024 + kb + scol, &Bsf[lds0 + i * 512]);
        }
        __syncthreads();
#pragma unroll
        for (int kk = 0; kk < 2; ++kk) {
            const int csw = ((kk * 4 + lhi) ^ (lrow & 7)) * 8;
            f16x8 axf[4];
#pragma unroll
            for (int mi = 0; mi < 4; ++mi)
                axf[mi] = *reinterpret_cast<const f16x8*>(&Asf[(arow + mi * 16) * 64 + csw]);
            __builtin_amdgcn_s_setprio(1);
#pragma unroll
            for (int ni = 0; ni < 4; ++ni) {
                f16x8 bf8 = *reinterpret_cast<const f16x8*>(&Bsf[(brow + ni * 16) * 64 + csw]);
#pragma unroll
                for (int mi = 0; mi < 4; ++mi)
                    acc[mi][ni] = MFMAH(axf[mi], bf8, acc[mi][ni]);
            }
            __builtin_amdgcn_s_setprio(0);
        }
        __syncthreads();
    }
    float bcol[4];
#pragma unroll
    for (int ni = 0; ni < 4; ++ni) bcol[ni] = bias[n0 + wc * 64 + ni * 16 + lrow];
    if (z == 2) {
        // V epilogue: write transposed vt[bh][d][s], 4 consecutive s per 8B store
#pragma unroll
        for (int mi = 0; mi < 4; ++mi) {
            const int m = m0 + wr * 64 + mi * 16 + lhi * 4;
            const int bb = m >> 11, s = m & 2047;
#pragma unroll
            for (int ni = 0; ni < 4; ++ni) {
                const int n = n0 + wc * 64 + ni * 16 + lrow;
                const int h = n >> 6, d = n & 63;
                ushort4 pk4;
                pk4.x = f2h(acc[mi][ni][0] + bcol[ni]);
                pk4.y = f2h(acc[mi][ni][1] + bcol[ni]);
                pk4.z = f2h(acc[mi][ni][2] + bcol[ni]);
                pk4.w = f2h(acc[mi][ni][3] + bcol[ni]);
                *reinterpret_cast<ushort4*>(vt + ((size_t)(bb * 16 + h) * 64 + d) * 2048 + s) = pk4;
            }
        }
    } else {
        const float qscale = (z == 0) ? 1.4426950408889634f : 1.0f;  // fold log2(e) into Q
        ushort* dst = (z == 0) ? qh : kh;
#pragma unroll
        for (int mi = 0; mi < 4; ++mi) {
#pragma unroll
            for (int r = 0; r < 4; ++r) {
                const int m = m0 + wr * 64 + mi * 16 + lhi * 4 + r;
                const int bb = m >> 11, s = m & 2047;
#pragma unroll
                for (int ni = 0; ni < 4; ++ni) {
                    const int n = n0 + wc * 64 + ni * 16 + lrow;
                    const int h = n >> 6, d = n & 63;
                    dst[((bb * 16 + h) * 2048 + s) * 64 + d] =
                        f2h((acc[mi][ni][r] + bcol[ni]) * qscale);
                }
            }
        }
    }
}

// ---- flash attention: paired tiles (quad LDS), m in C-operand, l on MFMA, raw exp ----
// Per pair: stage next pair; QK(a); QK(b) [MFMA overlaps sm(a) VALU]; sm(a)+PV(a);
// sm(b)+PV(b) [pend-shift if a rescaled]; ONE barrier.
__global__ __launch_bounds__(512, 4) void attn_fwd(const ushort* __restrict__ Qhg,
                                                   const ushort* __restrict__ Khg,
                                                   const ushort* __restrict__ Vtg,
                                                   float* __restrict__ out) {
    __shared__ ushort Ksh[4][64 * 64];
    __shared__ ushort Vts[4][64 * 64];
    const int tid = threadIdx.x;
    const int l = tid & 63, w = tid >> 6;          // 8 waves
    const int lrow = l & 15, lhi = l >> 4;
    const int wsub = w & 3;                        // wave's quarter within its q-tile
    const int qt = blockIdx.x * 2 + (w >> 2);      // waves 0-3 -> even qt, 4-7 -> odd
    const int bh = blockIdx.y;
    const int b = bh >> 4, h = bh & 15;
    const size_t qoff = ((size_t)bh * 2048 + qt * 64) * 64;
    const size_t kvoff = (size_t)bh * 2048 * 64;
    const size_t vtoff = (size_t)bh * 64 * 2048;

    // Q fragments (B-operand after the QK swap)
    f16x8 aqh[2];
#pragma unroll
    for (int kk = 0; kk < 2; ++kk) {
        const size_t qa = qoff + (wsub * 16 + lrow) * 64 + kk * 32 + lhi * 8;
        aqh[kk] = *reinterpret_cast<const f16x8*>(Qhg + qa);
    }

    // ones B-fragment (l = P x 1 on MFMA pipe)
    const f16x8 ones = {(f16)1, (f16)1, (f16)1, (f16)1, (f16)1, (f16)1, (f16)1, (f16)1};

    // staging: 8 waves x 8 rows x 64 cols; one gload per buffer per thread
    const int srow = w * 8 + (l >> 3);
    const int scol = ((l & 7) ^ (l >> 3)) * 8;    // pre-swizzled source col (rule #21)
    const int lds0 = w * 512;

    const int bl = (lhi << 4) + lhi * 4;          // broadcast lane base: + r

    float m_run = 0.f;                            // log2-domain running max
    f32x4 o[4];
    f32x4 l_acc = f32x4{0.f, 0.f, 0.f, 0.f};      // l in D-layout: q = lhi*4+r
#pragma unroll
    for (int ni = 0; ni < 4; ++ni) o[ni] = f32x4{0.f, 0.f, 0.f, 0.f};

    auto stage = [&](int buf, int t) {
        const size_t gk = kvoff + (size_t)(t * 64 + srow) * 64 + scol;
        const size_t gv = vtoff + (size_t)srow * 2048 + t * 64 + scol;
        gload_lds16(Khg + gk, &Ksh[buf][lds0]);
        gload_lds16(Vtg + gv, &Vts[buf][lds0]);
    };

    auto qk = [&](int buf, f32x4* sc) {
        // sc = S - m_baseline (baseline = m_run at issue time) via MFMA C-init
        const f32x4 minit = {-m_run, -m_run, -m_run, -m_run};
#pragma unroll
        for (int ni = 0; ni < 4; ++ni) sc[ni] = minit;
        __builtin_amdgcn_s_setprio(1);
#pragma unroll
        for (int kk = 0; kk < 2; ++kk) {
#pragma unroll
            for (int ni = 0; ni < 4; ++ni) {
                const int off = (ni * 16 + lrow) * 64 + (((kk * 4 + lhi) ^ (lrow & 7)) * 8);
                f16x8 khf = *reinterpret_cast<const f16x8*>(&Ksh[buf][off]);
                sc[ni] = MFMAH(khf, aqh[kk], sc[ni]);   // swapped operands
            }
        }
        __builtin_amdgcn_s_setprio(0);
    };

    // pend: per-thread shift applied to m_run AFTER this tile's qk was issued.
    // pendnz: wave-uniform flag. Returns delta applied by THIS call (0 if none).
    auto smpv = [&](f32x4* sc, int buf, float pend, bool pendnz) -> float {
        // row max relative to baked baseline — fmaxf triples fold to v_max3_f32
        float mx = fmaxf(fmaxf(sc[0][0], sc[0][1]), sc[0][2]);
        mx = fmaxf(fmaxf(mx, sc[0][3]), sc[1][0]);
        mx = fmaxf(fmaxf(mx, sc[1][1]), sc[1][2]);
        mx = fmaxf(fmaxf(mx, sc[1][3]), sc[2][0]);
        mx = fmaxf(fmaxf(mx, sc[2][1]), sc[2][2]);
        mx = fmaxf(fmaxf(mx, sc[2][3]), sc[3][0]);
        mx = fmaxf(fmaxf(mx, sc[3][1]), sc[3][2]);
        mx = fmaxf(mx, sc[3][3]);
        mx = fmaxf(mx, __shfl_xor(mx, 16, 64));
        mx = fmaxf(mx, __shfl_xor(mx, 32, 64));

        const float mrel = mx - pend;             // max relative to CURRENT m_run
        float p[4][4];
        float delta = 0.f;
        if (__any(mrel > 8.f)) {                  // rescale path (wave-uniform, rare)
            delta = fmaxf(mrel, 0.f);
            m_run += delta;
            const float shift = pend + delta;     // total shift from baked baseline
            const float alpha = exp2_raw(-delta);
#pragma unroll
            for (int ni = 0; ni < 4; ++ni)
#pragma unroll
                for (int rr = 0; rr < 4; ++rr)
                    p[ni][rr] = exp2_raw(sc[ni][rr] - shift);
            float ao0 = __shfl(alpha, bl + 0, 64);
            float ao1 = __shfl(alpha, bl + 1, 64);
            float ao2 = __shfl(alpha, bl + 2, 64);
            float ao3 = __shfl(alpha, bl + 3, 64);
#pragma unroll
            for (int ni = 0; ni < 4; ++ni) {
                o[ni][0] *= ao0; o[ni][1] *= ao1; o[ni][2] *= ao2; o[ni][3] *= ao3;
            }
            l_acc[0] *= ao0; l_acc[1] *= ao1; l_acc[2] *= ao2; l_acc[3] *= ao3;
        } else if (pendnz) {                      // a rescaled earlier in this pair
#pragma unroll
            for (int ni = 0; ni < 4; ++ni)
#pragma unroll
                for (int rr = 0; rr < 4; ++rr)
                    p[ni][rr] = exp2_raw(sc[ni][rr] - pend);
        } else {                                  // common: single v_exp_f32 each
#pragma unroll
            for (int ni = 0; ni < 4; ++ni)
#pragma unroll
                for (int rr = 0; rr < 4; ++rr)
                    p[ni][rr] = exp2_raw(sc[ni][rr]);
        }
        uint pk[4][2];
#pragma unroll
        for (int ni = 0; ni < 4; ++ni) {
            pk[ni][0] = pk_f16(p[ni][0], p[ni][1]);
            pk[ni][1] = pk_f16(p[ni][2], p[ni][3]);
        }
        // redistribute P into PV A-fragments (permlane pair, verified r13)
        uint apw[2][4];
#if HAVE_PERMLANE_SWAP
#pragma unroll
        for (int kk = 0; kk < 2; ++kk) {
#pragma unroll
            for (int c = 0; c < 2; ++c) {
                auto r1 = __builtin_amdgcn_permlane32_swap(pk[2 * kk][c], pk[2 * kk + 1][c],
                                                           false, false);
                auto r2 = __builtin_amdgcn_permlane16_swap(r1[0], r1[1], false, false);
                apw[kk][c]     = (uint)r2[0];
                apw[kk][2 + c] = (uint)r2[1];
            }
        }
#else
        const int s0 = lrow + 32 * (lhi & 1);
        const int s1 = s0 + 16;
        const bool abit = (lhi >> 1) != 0;
#pragma unroll
        for (int kk = 0; kk < 2; ++kk) {
            int t0, t1;
            t0 = __shfl((int)pk[2 * kk][0], s0, 64); t1 = __shfl((int)pk[2 * kk + 1][0], s0, 64);
            apw[kk][0] = (uint)(abit ? t1 : t0);
            t0 = __shfl((int)pk[2 * kk][1], s0, 64); t1 = __shfl((int)pk[2 * kk + 1][1], s0, 64);
            apw[kk][1] = (uint)(abit ? t1 : t0);
            t0 = __shfl((int)pk[2 * kk][0], s1, 64); t1 = __shfl((int)pk[2 * kk + 1][0], s1, 64);
            apw[kk][2] = (uint)(abit ? t1 : t0);
            t0 = __shfl((int)pk[2 * kk][1], s1, 64); t1 = __shfl((int)pk[2 * kk + 1][1], s1, 64);
            apw[kk][3] = (uint)(abit ? t1 : t0);
        }
#endif
        // O += P · V ; l_acc += P · 1 (MFMA pipe)
        __builtin_amdgcn_s_setprio(1);
#pragma unroll
        for (int kk = 0; kk < 2; ++kk) {
            f16x8 ap = *reinterpret_cast<const f16x8*>(&apw[kk][0]);
#pragma unroll
            for (int ni = 0; ni < 4; ++ni) {
                const int off = (ni * 16 + lrow) * 64 + (((kk * 4 + lhi) ^ (lrow & 7)) * 8);
                f16x8 vf = *reinterpret_cast<const f16x8*>(&Vts[buf][off]);
                o[ni] = MFMAH(ap, vf, o[ni]);
            }
            l_acc = MFMAH(ap, ones, l_acc);
        }
        __builtin_amdgcn_s_setprio(0);
        return delta;
    };

    // prologue: stage pair 0 into buffers 0,1
    stage(0, 0);
    stage(1, 1);
    __syncthreads();
#pragma unroll 1
    for (int pp = 0; pp < 16; ++pp) {
        const int ba = (pp & 1) * 2;           // this pair's buffers: ba, ba+1
        const int nb = ((pp + 1) & 1) * 2;     // next pair's buffers
        if (pp < 15) {
            stage(nb, 2 * pp + 2);             // prefetch next pair under compute
            stage(nb + 1, 2 * pp + 3);
        }
        f32x4 sca[4], scb[4];
        qk(ba, sca);                           // baseline = current m_run for BOTH
        qk(ba + 1, scb);                       // independent — overlaps sm(a) on MFMA pipe
        float da = smpv(sca, ba, 0.f, false);
        bool an = __any(da != 0.f);            // wave-uniform: did a rescale?
        smpv(scb, ba + 1, da, an);
        __syncthreads();                       // next-pair staging landed; reads done
    }

    // epilogue: 4 reciprocals + 16 multiplies
    const float inv0 = 1.f / l_acc[0];
    const float inv1 = 1.f / l_acc[1];
    const float inv2 = 1.f / l_acc[2];
    const float inv3 = 1.f / l_acc[3];
#pragma unroll
    for (int ni = 0; ni < 4; ++ni) {
        const int q = qt * 64 + wsub * 16 + lhi * 4;
        const int d = ni * 16 + lrow;
        float* op = out + ((size_t)b * 2048 + q) * 1024 + h * 64 + d;
        op[0]        = o[ni][0] * inv0;
        op[1024]     = o[ni][1] * inv1;
        op[2 * 1024] = o[ni][2] * inv2;
        op[3 * 1024] = o[ni][3] * inv3;
    }
}

extern "C" void kernel_launch(void* const* d_in, const int* in_sizes, int n_in,
                              void* d_out, int out_size, void* d_ws, size_t ws_size,
                              hipStream_t stream) {
    const float* x  = (const float*)d_in[0];
    const float* Wq = (const float*)d_in[1];
    const float* bq = (const float*)d_in[2];
    const float* Wk = (const float*)d_in[3];
    const float* bk = (const float*)d_in[4];
    const float* Wv = (const float*)d_in[5];
    const float* bv = (const float*)d_in[6];
    float* outp = (float*)d_out;

    ushort* ws = (ushort*)d_ws;
    const size_t XM = 4096 * 1024;
    const size_t WM = 1024 * 1024;
    ushort* xf = ws;                  // x fp16
    ushort* wf = xf + XM;             // Wq,Wk,Wv fp16 (3 x WM)
    ushort* qh = wf + 3 * WM;         // Q fp16 (log2e-scaled) [32][2048][64]
    ushort* kh = qh + XM;             // K fp16
    ushort* vt = kh + XM;             // V^T [bh][d][s] fp16

    cvt_all<<<3584, 256, 0, stream>>>(x, Wq, Wk, Wv, xf, wf);

    qkv_gemm<<<dim3(32, 8, 3), 256, 0, stream>>>(xf, wf, bq, bk, bv, qh, kh, vt);

    attn_fwd<<<dim3(16, 32), 512, 0, stream>>>(qh, kh, vt, outp);
}

// Round 24
// 93.946 us; speedup vs baseline: 1.0137x; 1.0137x over previous
//
#include <hip/hip_runtime.h>
#include <hip/hip_bf16.h>

typedef unsigned int uint;
typedef unsigned short ushort;
typedef _Float16 f16;
typedef __attribute__((ext_vector_type(4))) float f32x4;
typedef __attribute__((ext_vector_type(8))) _Float16 f16x8;
typedef __attribute__((ext_vector_type(8))) ushort ushort8;

#define MFMAH(a, b, c) __builtin_amdgcn_mfma_f32_16x16x32_f16((a), (b), (c), 0, 0, 0)

#if __has_builtin(__builtin_amdgcn_permlane32_swap) && __has_builtin(__builtin_amdgcn_permlane16_swap)
#define HAVE_PERMLANE_SWAP 1
#else
#define HAVE_PERMLANE_SWAP 0
#endif

// raw v_exp_f32: 1 instruction; denormal results flush to 0 (fine: P < 2^-126 is dead)
__device__ __forceinline__ float exp2_raw(float x) {
    return __builtin_amdgcn_exp2f(x);
}

__device__ __forceinline__ ushort f2h(float x) {
    f16 h = (f16)x;                       // RNE
    return __builtin_bit_cast(ushort, h);
}
// pack two f32 -> u32 of 2 fp16 (lo in [15:0]), RTZ — fine for P in [0,256]
__device__ __forceinline__ uint pk_f16(float lo, float hi) {
    auto t = __builtin_amdgcn_cvt_pkrtz(lo, hi);   // __fp16 ext_vector(2)
    return __builtin_bit_cast(uint, t);
}

__device__ __forceinline__ void gload_lds16(const void* g, void* l) {
    __builtin_amdgcn_global_load_lds(
        (const __attribute__((address_space(1))) void*)g,
        (__attribute__((address_space(3))) void*)l, 16, 0, 0);
}

// ------- fused fp32 -> fp16 conversion for x, Wq, Wk, Wv (one launch) -------
__global__ __launch_bounds__(256) void cvt_all(const float* __restrict__ x,
                                               const float* __restrict__ Wq,
                                               const float* __restrict__ Wk,
                                               const float* __restrict__ Wv,
                                               ushort* __restrict__ xf,
                                               ushort* __restrict__ wf) {
    const int blk = blockIdx.x;
    const float* src;
    ushort* dst;
    int i;   // 8-elem chunk index within the source
    if (blk < 2048) {
        src = x;  dst = xf;              i = blk * 256 + threadIdx.x;
    } else if (blk < 2560) {
        src = Wq; dst = wf;              i = (blk - 2048) * 256 + threadIdx.x;
    } else if (blk < 3072) {
        src = Wk; dst = wf + 1024 * 1024; i = (blk - 2560) * 256 + threadIdx.x;
    } else {
        src = Wv; dst = wf + 2 * 1024 * 1024; i = (blk - 3072) * 256 + threadIdx.x;
    }
    const float4* s4 = reinterpret_cast<const float4*>(src);
    float4 a = s4[2 * i], b = s4[2 * i + 1];
    float v[8] = {a.x, a.y, a.z, a.w, b.x, b.y, b.z, b.w};
    ushort8 o;
#pragma unroll
    for (int j = 0; j < 8; ++j) o[j] = f2h(v[j]);
    *reinterpret_cast<ushort8*>(dst + i * 8) = o;
}

// ---------------- fused QKV projection GEMM (fp16 single-term) ----------------
// z=0: Q scaled by log2(e), fp16. z=1: K fp16. z=2: V fp16, written TRANSPOSED
// to vt[bh][d][s].
__global__ __launch_bounds__(256, 3) void qkv_gemm(const ushort* __restrict__ xf,
                                                   const ushort* __restrict__ wf,
                                                   const float* __restrict__ bq,
                                                   const float* __restrict__ bk,
                                                   const float* __restrict__ bv,
                                                   ushort* __restrict__ qh,
                                                   ushort* __restrict__ kh,
                                                   ushort* __restrict__ vt) {
    __shared__ ushort Asf[128 * 64];
    __shared__ ushort Bsf[128 * 64];
    const int tid = threadIdx.x;
    const int l = tid & 63, w = tid >> 6;
    const int lrow = l & 15, lhi = l >> 4;
    const int wr = w >> 1, wc = w & 1;
    const int m0 = blockIdx.x * 128;
    const int n0 = blockIdx.y * 128;
    const int z = blockIdx.z;
    const ushort* wz = wf + z * (1024 * 1024);
    const float* bias = (z == 0) ? bq : (z == 1) ? bk : bv;

    f32x4 acc[4][4] = {};
    const int srow = w * 32 + (l >> 3);               // +i*8
    const int scol = ((l & 7) ^ (l >> 3)) * 8;        // pre-swizzled k-col (rule #21)
    const int lds0 = w * 2048;                        // +i*512
    const int arow = wr * 64 + lrow;
    const int brow = wc * 64 + lrow;

    for (int kt = 0; kt < 16; ++kt) {
        const int kb = kt * 64;
#pragma unroll
        for (int i = 0; i < 4; ++i) {
            gload_lds16(xf + (m0 + srow + i * 8) * 1024 + kb + scol, &Asf[lds0 + i * 512]);
            gload_lds16(wz + (n0 + srow + i * 8) * 1024 + kb + scol, &Bsf[lds0 + i * 512]);
        }
        __syncthreads();
#pragma unroll
        for (int kk = 0; kk < 2; ++kk) {
            const int csw = ((kk * 4 + lhi) ^ (lrow & 7)) * 8;
            f16x8 axf[4];
#pragma unroll
            for (int mi = 0; mi < 4; ++mi)
                axf[mi] = *reinterpret_cast<const f16x8*>(&Asf[(arow + mi * 16) * 64 + csw]);
            __builtin_amdgcn_s_setprio(1);
#pragma unroll
            for (int ni = 0; ni < 4; ++ni) {
                f16x8 bf8 = *reinterpret_cast<const f16x8*>(&Bsf[(brow + ni * 16) * 64 + csw]);
#pragma unroll
                for (int mi = 0; mi < 4; ++mi)
                    acc[mi][ni] = MFMAH(axf[mi], bf8, acc[mi][ni]);
            }
            __builtin_amdgcn_s_setprio(0);
        }
        __syncthreads();
    }
    float bcol[4];
#pragma unroll
    for (int ni = 0; ni < 4; ++ni) bcol[ni] = bias[n0 + wc * 64 + ni * 16 + lrow];
    if (z == 2) {
        // V epilogue: write transposed vt[bh][d][s], 4 consecutive s per 8B store
#pragma unroll
        for (int mi = 0; mi < 4; ++mi) {
            const int m = m0 + wr * 64 + mi * 16 + lhi * 4;
            const int bb = m >> 11, s = m & 2047;
#pragma unroll
            for (int ni = 0; ni < 4; ++ni) {
                const int n = n0 + wc * 64 + ni * 16 + lrow;
                const int h = n >> 6, d = n & 63;
                ushort4 pk4;
                pk4.x = f2h(acc[mi][ni][0] + bcol[ni]);
                pk4.y = f2h(acc[mi][ni][1] + bcol[ni]);
                pk4.z = f2h(acc[mi][ni][2] + bcol[ni]);
                pk4.w = f2h(acc[mi][ni][3] + bcol[ni]);
                *reinterpret_cast<ushort4*>(vt + ((size_t)(bb * 16 + h) * 64 + d) * 2048 + s) = pk4;
            }
        }
    } else {
        const float qscale = (z == 0) ? 1.4426950408889634f : 1.0f;  // fold log2(e) into Q
        ushort* dst = (z == 0) ? qh : kh;
#pragma unroll
        for (int mi = 0; mi < 4; ++mi) {
#pragma unroll
            for (int r = 0; r < 4; ++r) {
                const int m = m0 + wr * 64 + mi * 16 + lhi * 4 + r;
                const int bb = m >> 11, s = m & 2047;
#pragma unroll
                for (int ni = 0; ni < 4; ++ni) {
                    const int n = n0 + wc * 64 + ni * 16 + lrow;
                    const int h = n >> 6, d = n & 63;
                    dst[((bb * 16 + h) * 2048 + s) * 64 + d] =
                        f2h((acc[mi][ni][r] + bcol[ni]) * qscale);
                }
            }
        }
    }
}

// ---- flash attention: 8 waves / 2 q-tiles; m in C-operand; l on MFMA; raw v_exp ----
__global__ __launch_bounds__(512, 4) void attn_fwd(const ushort* __restrict__ Qhg,
                                                   const ushort* __restrict__ Khg,
                                                   const ushort* __restrict__ Vtg,
                                                   float* __restrict__ out) {
    __shared__ ushort Ksh[2][64 * 64];
    __shared__ ushort Vts[2][64 * 64];
    const int tid = threadIdx.x;
    const int l = tid & 63, w = tid >> 6;          // 8 waves
    const int lrow = l & 15, lhi = l >> 4;
    const int wsub = w & 3;                        // wave's quarter within its q-tile
    const int qt = blockIdx.x * 2 + (w >> 2);      // waves 0-3 -> even qt, 4-7 -> odd
    const int bh = blockIdx.y;
    const int b = bh >> 4, h = bh & 15;
    const size_t qoff = ((size_t)bh * 2048 + qt * 64) * 64;
    const size_t kvoff = (size_t)bh * 2048 * 64;
    const size_t vtoff = (size_t)bh * 64 * 2048;

    // Q fragments (B-operand after the QK swap)
    f16x8 aqh[2];
#pragma unroll
    for (int kk = 0; kk < 2; ++kk) {
        const size_t qa = qoff + (wsub * 16 + lrow) * 64 + kk * 32 + lhi * 8;
        aqh[kk] = *reinterpret_cast<const f16x8*>(Qhg + qa);
    }

    // ones B-fragment: layout-independent constant splat (for l = P x 1 on MFMA pipe)
    const f16x8 ones = {(f16)1, (f16)1, (f16)1, (f16)1, (f16)1, (f16)1, (f16)1, (f16)1};

    // staging: 8 waves x 8 rows x 64 cols; one gload per buffer per thread
    const int srow = w * 8 + (l >> 3);
    const int scol = ((l & 7) ^ (l >> 3)) * 8;    // pre-swizzled source col (rule #21)
    const int lds0 = w * 512;

    const int bl = (lhi << 4) + lhi * 4;          // broadcast lane base: + r

    float m_run = 0.f;                            // log2-domain running max (init 0: first
                                                  // tile rescales; o=l=0 so it's harmless)
    f32x4 o[4];
    f32x4 l_acc = f32x4{0.f, 0.f, 0.f, 0.f};      // l in D-layout: q = lhi*4+r (dup over lrow)
#pragma unroll
    for (int ni = 0; ni < 4; ++ni) o[ni] = f32x4{0.f, 0.f, 0.f, 0.f};

    auto stage = [&](int buf, int t) {
        const size_t gk = kvoff + (size_t)(t * 64 + srow) * 64 + scol;
        const size_t gv = vtoff + (size_t)srow * 2048 + t * 64 + scol;
        gload_lds16(Khg + gk, &Ksh[buf][lds0]);
        gload_lds16(Vtg + gv, &Vts[buf][lds0]);
    };

    auto tilecomp = [&](int buf) {
        // sc = S - m_old via MFMA C-operand init (saves 16 v_sub before exp2)
        f32x4 sc[4];
        const f32x4 minit = {-m_run, -m_run, -m_run, -m_run};
#pragma unroll
        for (int ni = 0; ni < 4; ++ni) sc[ni] = minit;
        __builtin_amdgcn_s_setprio(1);
#pragma unroll
        for (int kk = 0; kk < 2; ++kk) {
#pragma unroll
            for (int ni = 0; ni < 4; ++ni) {
                const int off = (ni * 16 + lrow) * 64 + (((kk * 4 + lhi) ^ (lrow & 7)) * 8);
                f16x8 khf = *reinterpret_cast<const f16x8*>(&Ksh[buf][off]);
                sc[ni] = MFMAH(khf, aqh[kk], sc[ni]);   // swapped operands
            }
        }
        __builtin_amdgcn_s_setprio(0);

        // relative row max (vs m_old) — fmaxf triples fold to v_max3_f32
        float mx = fmaxf(fmaxf(sc[0][0], sc[0][1]), sc[0][2]);
        mx = fmaxf(fmaxf(mx, sc[0][3]), sc[1][0]);
        mx = fmaxf(fmaxf(mx, sc[1][1]), sc[1][2]);
        mx = fmaxf(fmaxf(mx, sc[1][3]), sc[2][0]);
        mx = fmaxf(fmaxf(mx, sc[2][1]), sc[2][2]);
        mx = fmaxf(fmaxf(mx, sc[2][3]), sc[3][0]);
        mx = fmaxf(fmaxf(mx, sc[3][1]), sc[3][2]);
        mx = fmaxf(mx, sc[3][3]);
        mx = fmaxf(mx, __shfl_xor(mx, 16, 64));
        mx = fmaxf(mx, __shfl_xor(mx, 32, 64));

        float p[4][4];
        if (__any(mx > 8.f)) {                    // rescale path (wave-uniform, rare)
            const float delta = fmaxf(mx, 0.f);   // m_new - m_old for this q-row
            m_run += delta;
            const float alpha = exp2_raw(-delta);
#pragma unroll
            for (int ni = 0; ni < 4; ++ni)
#pragma unroll
                for (int rr = 0; rr < 4; ++rr)
                    p[ni][rr] = exp2_raw(sc[ni][rr] - delta);
            float ao0 = __shfl(alpha, bl + 0, 64);
            float ao1 = __shfl(alpha, bl + 1, 64);
            float ao2 = __shfl(alpha, bl + 2, 64);
            float ao3 = __shfl(alpha, bl + 3, 64);
#pragma unroll
            for (int ni = 0; ni < 4; ++ni) {
                o[ni][0] *= ao0; o[ni][1] *= ao1; o[ni][2] *= ao2; o[ni][3] *= ao3;
            }
            l_acc[0] *= ao0; l_acc[1] *= ao1; l_acc[2] *= ao2; l_acc[3] *= ao3;
        } else {                                  // common path: single v_exp_f32 each
#pragma unroll
            for (int ni = 0; ni < 4; ++ni)
#pragma unroll
                for (int rr = 0; rr < 4; ++rr)
                    p[ni][rr] = exp2_raw(sc[ni][rr]);
        }
        uint pk[4][2];
#pragma unroll
        for (int ni = 0; ni < 4; ++ni) {
            pk[ni][0] = pk_f16(p[ni][0], p[ni][1]);
            pk[ni][1] = pk_f16(p[ni][2], p[ni][3]);
        }
        // redistribute P into PV A-fragments (permlane pair, verified r13)
        uint apw[2][4];
#if HAVE_PERMLANE_SWAP
#pragma unroll
        for (int kk = 0; kk < 2; ++kk) {
#pragma unroll
            for (int c = 0; c < 2; ++c) {
                auto r1 = __builtin_amdgcn_permlane32_swap(pk[2 * kk][c], pk[2 * kk + 1][c],
                                                           false, false);
                auto r2 = __builtin_amdgcn_permlane16_swap(r1[0], r1[1], false, false);
                apw[kk][c]     = (uint)r2[0];
                apw[kk][2 + c] = (uint)r2[1];
            }
        }
#else
        const int s0 = lrow + 32 * (lhi & 1);
        const int s1 = s0 + 16;
        const bool abit = (lhi >> 1) != 0;
#pragma unroll
        for (int kk = 0; kk < 2; ++kk) {
            int t0, t1;
            t0 = __shfl((int)pk[2 * kk][0], s0, 64); t1 = __shfl((int)pk[2 * kk + 1][0], s0, 64);
            apw[kk][0] = (uint)(abit ? t1 : t0);
            t0 = __shfl((int)pk[2 * kk][1], s0, 64); t1 = __shfl((int)pk[2 * kk + 1][1], s0, 64);
            apw[kk][1] = (uint)(abit ? t1 : t0);
            t0 = __shfl((int)pk[2 * kk][0], s1, 64); t1 = __shfl((int)pk[2 * kk + 1][0], s1, 64);
            apw[kk][2] = (uint)(abit ? t1 : t0);
            t0 = __shfl((int)pk[2 * kk][1], s1, 64); t1 = __shfl((int)pk[2 * kk + 1][1], s1, 64);
            apw[kk][3] = (uint)(abit ? t1 : t0);
        }
#endif
        // O += P · V ; l_acc += P · 1 (MFMA pipe)
        __builtin_amdgcn_s_setprio(1);
#pragma unroll
        for (int kk = 0; kk < 2; ++kk) {
            f16x8 ap = *reinterpret_cast<const f16x8*>(&apw[kk][0]);
#pragma unroll
            for (int ni = 0; ni < 4; ++ni) {
                const int off = (ni * 16 + lrow) * 64 + (((kk * 4 + lhi) ^ (lrow & 7)) * 8);
                f16x8 vf = *reinterpret_cast<const f16x8*>(&Vts[buf][off]);
                o[ni] = MFMAH(ap, vf, o[ni]);
            }
            l_acc = MFMAH(ap, ones, l_acc);
        }
        __builtin_amdgcn_s_setprio(0);
    };

    stage(0, 0);
    __syncthreads();
#pragma unroll 1
    for (int tt = 0; tt < 16; ++tt) {
        stage(1, tt * 2 + 1);          // prefetch odd tile while computing even
        tilecomp(0);
        __syncthreads();               // buf1 ready; everyone done reading buf0
        if (tt < 15) stage(0, tt * 2 + 2);
        tilecomp(1);
        __syncthreads();
    }

    // epilogue: 4 reciprocals + 16 multiplies (vs 16 divides)
    const float inv0 = 1.f / l_acc[0];
    const float inv1 = 1.f / l_acc[1];
    const float inv2 = 1.f / l_acc[2];
    const float inv3 = 1.f / l_acc[3];
#pragma unroll
    for (int ni = 0; ni < 4; ++ni) {
        const int q = qt * 64 + wsub * 16 + lhi * 4;
        const int d = ni * 16 + lrow;
        float* op = out + ((size_t)b * 2048 + q) * 1024 + h * 64 + d;
        op[0]        = o[ni][0] * inv0;
        op[1024]     = o[ni][1] * inv1;
        op[2 * 1024] = o[ni][2] * inv2;
        op[3 * 1024] = o[ni][3] * inv3;
    }
}

extern "C" void kernel_launch(void* const* d_in, const int* in_sizes, int n_in,
                              void* d_out, int out_size, void* d_ws, size_t ws_size,
                              hipStream_t stream) {
    const float* x  = (const float*)d_in[0];
    const float* Wq = (const float*)d_in[1];
    const float* bq = (const float*)d_in[2];
    const float* Wk = (const float*)d_in[3];
    const float* bk = (const float*)d_in[4];
    const float* Wv = (const float*)d_in[5];
    const float* bv = (const float*)d_in[6];
    float* outp = (float*)d_out;

    ushort* ws = (ushort*)d_ws;
    const size_t XM = 4096 * 1024;
    const size_t WM = 1024 * 1024;
    ushort* xf = ws;                  // x fp16
    ushort* wf = xf + XM;             // Wq,Wk,Wv fp16 (3 x WM)
    ushort* qh = wf + 3 * WM;         // Q fp16 (log2e-scaled) [32][2048][64]
    ushort* kh = qh + XM;             // K fp16
    ushort* vt = kh + XM;             // V^T [bh][d][s] fp16

    cvt_all<<<3584, 256, 0, stream>>>(x, Wq, Wk, Wv, xf, wf);

    qkv_gemm<<<dim3(32, 8, 3), 256, 0, stream>>>(xf, wf, bq, bk, bv, qh, kh, vt);

    attn_fwd<<<dim3(16, 32), 512, 0, stream>>>(qh, kh, vt, outp);
}